// Round 1
// baseline (569.974 us; speedup 1.0000x reference)
//
#include <hip/hip_runtime.h>

// ---------------------------------------------------------------------------
// LinearAttention on MI355X (gfx950), round 1: correctness-first bf16 MFMA.
// Pipeline: fill attn_weights || cvt q/k/v -> bf16 || transpose-cvt weights
//  -> proj GEMMs (Qp,Kp,Vp) -> feature-map GEMMs (Qf,Kf) -> denom(Kf)
//  -> KV^T partial + reduce/scale -> batched QKV GEMM -> output GEMM (fp32).
// ---------------------------------------------------------------------------

typedef __bf16 bf16_t;
typedef __bf16 bf16x8 __attribute__((ext_vector_type(8)));
typedef __bf16 bf16x4 __attribute__((ext_vector_type(4)));
typedef float  f32x4  __attribute__((ext_vector_type(4)));

#define NTOK   4096L        // B*S
#define HID    2048L
#define NH     16
#define HD     128L

// async global->LDS, 16B per lane. LDS dest must be linear: base + lane*16.
__device__ __forceinline__ void gload16(const void* g, void* l) {
  __builtin_amdgcn_global_load_lds(
      (__attribute__((address_space(1))) void*)(g),
      (__attribute__((address_space(3))) void*)(l), 16, 0, 0);
}

// ---------------------------------------------------------------------------
// m97-style bf16 GEMM, C[M,N] = A[M,K] @ Bt[N,K]^T (+bias) (opt relu).
// 128x128 tile, BK=64, 256 threads (4 waves in 2x2), 4x4 16x16 frags/wave.
// Batched via grid.z: z = zb*HperB + zh, per-tensor (batchB, batchH) strides.
// ---------------------------------------------------------------------------
template<bool RELU, bool OUTF32, bool BIAS>
__global__ __launch_bounds__(256) void gemm_bt(
    const bf16_t* __restrict__ A, const bf16_t* __restrict__ Bt,
    const float* __restrict__ bias, void* __restrict__ C,
    int K, int lda, int ldb, int ldc,
    long aBatchB, long aBatchH, long bBatchB, long bBatchH,
    long cBatchB, long cBatchH, int HperB)
{
  __shared__ bf16_t As[128 * 64];
  __shared__ bf16_t Bs[128 * 64];

  const int z  = blockIdx.z;
  const int zb = z / HperB, zh = z % HperB;
  const bf16_t* Ab = A  + (long)zb * aBatchB + (long)zh * aBatchH
                        + (long)blockIdx.y * 128 * lda;
  const bf16_t* Bb = Bt + (long)zb * bBatchB + (long)zh * bBatchH
                        + (long)blockIdx.x * 128 * ldb;

  const int t = threadIdx.x;
  const int lane = t & 63, w = t >> 6;
  const int wm = (w >> 1) * 64, wn = (w & 1) * 64;

  f32x4 acc[4][4];
#pragma unroll
  for (int i = 0; i < 4; ++i)
#pragma unroll
    for (int j = 0; j < 4; ++j) acc[i][j] = (f32x4){0.f, 0.f, 0.f, 0.f};

  for (int k0 = 0; k0 < K; k0 += 64) {
#pragma unroll
    for (int i = 0; i < 4; ++i) {           // 1024 chunks of 16B per tensor
      int c = i * 256 + t;
      int row = c >> 3, col = (c & 7) * 8;
      gload16(Ab + (long)row * lda + k0 + col, &As[c * 8]);
      gload16(Bb + (long)row * ldb + k0 + col, &Bs[c * 8]);
    }
    __syncthreads();                        // drains vmcnt before barrier
#pragma unroll
    for (int kk = 0; kk < 2; ++kk) {
      bf16x8 af[4], bf[4];
#pragma unroll
      for (int mi = 0; mi < 4; ++mi)
        af[mi] = *(const bf16x8*)&As[(wm + mi * 16 + (lane & 15)) * 64
                                     + kk * 32 + (lane >> 4) * 8];
#pragma unroll
      for (int ni = 0; ni < 4; ++ni)
        bf[ni] = *(const bf16x8*)&Bs[(wn + ni * 16 + (lane & 15)) * 64
                                     + kk * 32 + (lane >> 4) * 8];
#pragma unroll
      for (int mi = 0; mi < 4; ++mi)
#pragma unroll
        for (int ni = 0; ni < 4; ++ni)
          acc[mi][ni] = __builtin_amdgcn_mfma_f32_16x16x32_bf16(
              af[mi], bf[ni], acc[mi][ni], 0, 0, 0);
    }
    __syncthreads();
  }

  // Epilogue. D mapping (m89-verified): col = lane&15, row = (lane>>4)*4 + j.
  const long cb = (long)zb * cBatchB + (long)zh * cBatchH;
  const int row0 = blockIdx.y * 128 + wm;
  const int col0 = blockIdx.x * 128 + wn;
#pragma unroll
  for (int mi = 0; mi < 4; ++mi) {
#pragma unroll
    for (int ni = 0; ni < 4; ++ni) {
      const int col = col0 + ni * 16 + (lane & 15);
      const float bv = BIAS ? bias[col] : 0.f;
#pragma unroll
      for (int j = 0; j < 4; ++j) {
        const int row = row0 + mi * 16 + (lane >> 4) * 4 + j;
        float v = acc[mi][ni][j] + bv;
        if (RELU) v = fmaxf(v, 0.f);
        if (OUTF32) ((float*)C)[cb + (long)row * ldc + col] = v;
        else        ((bf16_t*)C)[cb + (long)row * ldc + col] = (bf16_t)v;
      }
    }
  }
}

// ---------------------------------------------------------------------------
__global__ void fill_f32(float* __restrict__ p, float v, long n4) {
  long i = (long)blockIdx.x * blockDim.x + threadIdx.x;
  const long stride = (long)gridDim.x * blockDim.x;
  const float4 val = make_float4(v, v, v, v);
  for (; i < n4; i += stride) ((float4*)p)[i] = val;
}

__global__ void f32_to_bf16(const float* __restrict__ in,
                            bf16_t* __restrict__ out, long n) {
  long i = ((long)blockIdx.x * blockDim.x + threadIdx.x) * 4;
  const long stride = (long)gridDim.x * blockDim.x * 4;
  for (; i < n; i += stride) {
    float4 v = *(const float4*)&in[i];
    bf16x4 o = { (bf16_t)v.x, (bf16_t)v.y, (bf16_t)v.z, (bf16_t)v.w };
    *(bf16x4*)&out[i] = o;
  }
}

// W[Kd][Nd] fp32 (ld=Nd)  ->  Wt[Nd][Kd] bf16 (ld=Kd)
__global__ void transpose_cvt(const float* __restrict__ W,
                              bf16_t* __restrict__ Wt, int Kd, int Nd) {
  __shared__ float tile[32][33];
  const int n0 = blockIdx.x * 32, k0 = blockIdx.y * 32;
  const int x = threadIdx.x, y = threadIdx.y;
#pragma unroll
  for (int j = 0; j < 32; j += 8)
    tile[y + j][x] = W[(long)(k0 + y + j) * Nd + n0 + x];
  __syncthreads();
#pragma unroll
  for (int j = 0; j < 32; j += 8)
    Wt[(long)(n0 + y + j) * Kd + k0 + x] = (bf16_t)tile[x][y + j];
}

// denom[z=b*16+h] = sum over (s,d) of Kf + 1e-8
__global__ void denom_kernel(const bf16_t* __restrict__ Kf,
                             float* __restrict__ denom) {
  const int z = blockIdx.x, b = z >> 4, h = z & 15;
  const bf16_t* base = Kf + (long)b * (NTOK / 2) * HID + h * HD;
  const int t = threadIdx.x;
  float s = 0.f;
  for (int i = t; i < 2048 * 16; i += 256) {     // 2048 rows x 16 segs of 8
    int r = i >> 4, seg = i & 15;
    bf16x8 v = *(const bf16x8*)&base[(long)r * HID + seg * 8];
#pragma unroll
    for (int j = 0; j < 8; ++j) s += (float)v[j];
  }
#pragma unroll
  for (int off = 32; off; off >>= 1) s += __shfl_down(s, off, 64);
  __shared__ float red[4];
  if ((t & 63) == 0) red[t >> 6] = s;
  __syncthreads();
  if (t == 0) denom[z] = red[0] + red[1] + red[2] + red[3] + 1e-8f;
}

// Partial KV^T: part[sch][z][e][d] = sum_{s in chunk} V[s,e] * K[s,d]
__global__ __launch_bounds__(256) void kv_partial(
    const bf16_t* __restrict__ Kf, const bf16_t* __restrict__ Vp,
    float* __restrict__ part) {
  const int z = blockIdx.y, b = z >> 4, h = z & 15;
  const int s0 = blockIdx.x * 128;
  const int t = threadIdx.x;
  __shared__ bf16_t Ks[32 * 128];
  __shared__ bf16_t Vs[32 * 128];
  const bf16_t* Kb = Kf + (long)b * 4194304 + h * HD;
  const bf16_t* Vb = Vp + (long)b * 4194304 + h * HD;
  float acc[8][8];
#pragma unroll
  for (int i = 0; i < 8; ++i)
#pragma unroll
    for (int j = 0; j < 8; ++j) acc[i][j] = 0.f;
  const int d0 = (t & 15) * 8, e0 = (t >> 4) * 8;
  for (int sc = 0; sc < 128; sc += 32) {
#pragma unroll
    for (int i = 0; i < 2; ++i) {
      int idx = (i * 256 + t) * 8;
      int r = idx >> 7, c = idx & 127;
      long g = (long)(s0 + sc + r) * HID + c;
      *(bf16x8*)&Ks[r * 128 + c] = *(const bf16x8*)&Kb[g];
      *(bf16x8*)&Vs[r * 128 + c] = *(const bf16x8*)&Vb[g];
    }
    __syncthreads();
    for (int s = 0; s < 32; ++s) {
      bf16x8 kv = *(const bf16x8*)&Ks[s * 128 + d0];
      bf16x8 vv = *(const bf16x8*)&Vs[s * 128 + e0];
      float kf[8], vf[8];
#pragma unroll
      for (int i = 0; i < 8; ++i) { kf[i] = (float)kv[i]; vf[i] = (float)vv[i]; }
#pragma unroll
      for (int i = 0; i < 8; ++i)
#pragma unroll
        for (int j = 0; j < 8; ++j) acc[i][j] += vf[i] * kf[j];
    }
    __syncthreads();
  }
  float* pb = part + ((long)blockIdx.x * 32 + z) * 16384;
#pragma unroll
  for (int i = 0; i < 8; ++i)
#pragma unroll
    for (int j = 0; j < 8; ++j)
      pb[(e0 + i) * 128 + (d0 + j)] = acc[i][j];
}

// KVT[z][e][d] = (sum_sch part) / denom[z], as bf16
__global__ void kv_reduce(const float* __restrict__ part,
                          const float* __restrict__ denom,
                          bf16_t* __restrict__ KVT) {
  const int z = blockIdx.x;
  const float inv = 1.0f / denom[z];
  for (int i = threadIdx.x; i < 16384; i += 256) {
    float s = 0.f;
#pragma unroll
    for (int c = 0; c < 16; ++c) s += part[((long)c * 32 + z) * 16384 + i];
    KVT[(long)z * 16384 + i] = (bf16_t)(s * inv);
  }
}

// ---------------------------------------------------------------------------
extern "C" void kernel_launch(void* const* d_in, const int* in_sizes, int n_in,
                              void* d_out, int out_size, void* d_ws, size_t ws_size,
                              hipStream_t stream) {
  (void)in_sizes; (void)n_in; (void)out_size; (void)ws_size;
  const float* q   = (const float*)d_in[0];
  const float* k   = (const float*)d_in[1];
  const float* v   = (const float*)d_in[2];
  const float* Wq  = (const float*)d_in[3];
  const float* bq  = (const float*)d_in[4];
  const float* Wk  = (const float*)d_in[5];
  const float* bk  = (const float*)d_in[6];
  const float* Wv  = (const float*)d_in[7];
  const float* bv  = (const float*)d_in[8];
  const float* Wo  = (const float*)d_in[9];
  const float* bo  = (const float*)d_in[10];
  const float* Wf1 = (const float*)d_in[11];
  const float* bf1 = (const float*)d_in[12];
  const float* Wf2 = (const float*)d_in[13];
  const float* bf2 = (const float*)d_in[14];

  // ws layout (bf16 elements; partials reuse the q_bf/k_bf region later)
  bf16_t* P     = (bf16_t*)d_ws;
  bf16_t* q_bf  = P;
  bf16_t* k_bf  = P + 8388608L;
  bf16_t* v_bf  = P + 16777216L;
  bf16_t* Wq_t  = P + 25165824L;
  bf16_t* Wk_t  = P + 29360128L;
  bf16_t* Wv_t  = P + 33554432L;
  bf16_t* Wo_t  = P + 37748736L;
  bf16_t* Wf1_t = P + 41943040L;   // [256][128]
  bf16_t* Wf2_t = P + 41975808L;   // [128][256]
  bf16_t* Qp    = P + 42008576L;   // [4096][2048] == [65536][128]
  bf16_t* Kp    = P + 50397184L;
  bf16_t* Vp    = P + 58785792L;   // later reused as context
  bf16_t* H1    = P + 67174400L;   // [65536][256]
  bf16_t* Qf    = P + 83951616L;
  bf16_t* Kf    = P + 92340224L;
  bf16_t* KVT   = P + 100728832L;  // [32][128][128]
  float*  denom = (float*)(P + 101253120L);
  float*  part  = (float*)d_ws;    // [16][32][128][128] f32, over dead q_bf/k_bf

  float* out0 = (float*)d_out;                 // [2,2048,2048]
  float* attn = (float*)d_out + 8388608L;      // [2,16,2048,2048]

  dim3 blk(256);

  // attn_weights = 1/2048
  fill_f32<<<2048, blk, 0, stream>>>(attn, 1.0f / 2048.0f, 33554432L);

  // fp32 -> bf16
  f32_to_bf16<<<8192, blk, 0, stream>>>(q, q_bf, 8388608L);
  f32_to_bf16<<<8192, blk, 0, stream>>>(k, k_bf, 8388608L);
  f32_to_bf16<<<8192, blk, 0, stream>>>(v, v_bf, 8388608L);

  // weight transposes: W[K][N] -> Wt[N][K] bf16
  transpose_cvt<<<dim3(64, 64), dim3(32, 8), 0, stream>>>(Wq, Wq_t, 2048, 2048);
  transpose_cvt<<<dim3(64, 64), dim3(32, 8), 0, stream>>>(Wk, Wk_t, 2048, 2048);
  transpose_cvt<<<dim3(64, 64), dim3(32, 8), 0, stream>>>(Wv, Wv_t, 2048, 2048);
  transpose_cvt<<<dim3(64, 64), dim3(32, 8), 0, stream>>>(Wo, Wo_t, 2048, 2048);
  transpose_cvt<<<dim3(8, 4),  dim3(32, 8), 0, stream>>>(Wf1, Wf1_t, 128, 256);
  transpose_cvt<<<dim3(4, 8),  dim3(32, 8), 0, stream>>>(Wf2, Wf2_t, 256, 128);

  // projections: [4096,2048] @ [2048,2048]
  gemm_bt<false, false, true><<<dim3(16, 32, 1), blk, 0, stream>>>(
      q_bf, Wq_t, bq, Qp, 2048, 2048, 2048, 2048, 0, 0, 0, 0, 0, 0, 1);
  gemm_bt<false, false, true><<<dim3(16, 32, 1), blk, 0, stream>>>(
      k_bf, Wk_t, bk, Kp, 2048, 2048, 2048, 2048, 0, 0, 0, 0, 0, 0, 1);
  gemm_bt<false, false, true><<<dim3(16, 32, 1), blk, 0, stream>>>(
      v_bf, Wv_t, bv, Vp, 2048, 2048, 2048, 2048, 0, 0, 0, 0, 0, 0, 1);

  // feature map Q: H1 = relu(Qp@Wf1+bf1) [65536,256]; Qf = H1@Wf2+bf2 [65536,128]
  gemm_bt<true, false, true><<<dim3(2, 512, 1), blk, 0, stream>>>(
      Qp, Wf1_t, bf1, H1, 128, 128, 128, 256, 0, 0, 0, 0, 0, 0, 1);
  gemm_bt<false, false, true><<<dim3(1, 512, 1), blk, 0, stream>>>(
      H1, Wf2_t, bf2, Qf, 256, 256, 256, 128, 0, 0, 0, 0, 0, 0, 1);
  // feature map K
  gemm_bt<true, false, true><<<dim3(2, 512, 1), blk, 0, stream>>>(
      Kp, Wf1_t, bf1, H1, 128, 128, 128, 256, 0, 0, 0, 0, 0, 0, 1);
  gemm_bt<false, false, true><<<dim3(1, 512, 1), blk, 0, stream>>>(
      H1, Wf2_t, bf2, Kf, 256, 256, 256, 128, 0, 0, 0, 0, 0, 0, 1);

  // denominator per (b,h)
  denom_kernel<<<32, blk, 0, stream>>>(Kf, denom);

  // KV^T = V^T K per head (split-S partials, then reduce + 1/denom scale)
  kv_partial<<<dim3(16, 32), blk, 0, stream>>>(Kf, Vp, part);
  kv_reduce<<<32, blk, 0, stream>>>(part, denom, KVT);

  // context = Qf @ KVT^T (batched over 32 (b,h)); overwrite Vp region
  gemm_bt<false, false, false><<<dim3(1, 16, 32), blk, 0, stream>>>(
      Qf, KVT, nullptr, Vp, 128, 2048, 128, 2048,
      4194304L, 128L, 262144L, 16384L, 4194304L, 128L, 16);

  // output = context @ Wo + bo  (fp32 -> d_out)
  gemm_bt<false, true, true><<<dim3(16, 32, 1), blk, 0, stream>>>(
      Vp, Wo_t, bo, out0, 2048, 2048, 2048, 2048, 0, 0, 0, 0, 0, 0, 1);
}

// Round 3
// 444.738 us; speedup vs baseline: 1.2816x; 1.2816x over previous
//
#include <hip/hip_runtime.h>

// ---------------------------------------------------------------------------
// LinearAttention on MI355X (gfx950), round 3 (= round 2 with compile fix).
//  - attn_weights fill distributed into the two big GEMMs (nontemporal stores)
//  - Q/K/V projections fused along M into one 12288x2048x2048 GEMM
//  - feature-map MLP (d->2d->relu->d) fused into one kernel, H in swizzled LDS
//  - cvt / big transposes merged into single launches
// ---------------------------------------------------------------------------

typedef __bf16 bf16_t;
typedef __bf16 bf16x8 __attribute__((ext_vector_type(8)));
typedef __bf16 bf16x4 __attribute__((ext_vector_type(4)));
typedef float  f32x4  __attribute__((ext_vector_type(4)));

#define FILLV (1.0f / 2048.0f)

// async global->LDS, 16B per lane. LDS dest must be linear: base + lane*16.
__device__ __forceinline__ void gload16(const void* g, void* l) {
  __builtin_amdgcn_global_load_lds(
      (__attribute__((address_space(1))) void*)(g),
      (__attribute__((address_space(3))) void*)(l), 16, 0, 0);
}

// ---------------------------------------------------------------------------
// Generic m97-style bf16 GEMM, C[M,N] = A[M,K] @ Bt[N,K]^T (+bias).
// 128x128 tile, BK=64, 256 threads (4 waves 2x2), 4x4 16x16x32 frags/wave.
// FILL: also writes 2 float4 of attn fill per thread per K-iter.
// ---------------------------------------------------------------------------
template<bool RELU, bool OUTF32, bool BIAS, bool FILL>
__global__ __launch_bounds__(256) void gemm_bt(
    const bf16_t* __restrict__ A, const bf16_t* __restrict__ Bt,
    const float* __restrict__ bias, void* __restrict__ C,
    int K, int lda, int ldb, int ldc,
    long aBatchB, long aBatchH, long bBatchB, long bBatchH,
    long cBatchB, long cBatchH, int HperB,
    float* __restrict__ attn, long fillBase)
{
  __shared__ bf16_t As[128 * 64];
  __shared__ bf16_t Bs[128 * 64];

  const int z  = blockIdx.z;
  const int zb = z / HperB, zh = z % HperB;
  const bf16_t* Ab = A  + (long)zb * aBatchB + (long)zh * aBatchH
                        + (long)blockIdx.y * 128 * lda;
  const bf16_t* Bb = Bt + (long)zb * bBatchB + (long)zh * bBatchH
                        + (long)blockIdx.x * 128 * ldb;

  const int t = threadIdx.x;
  const int lane = t & 63, w = t >> 6;
  const int wm = (w >> 1) * 64, wn = (w & 1) * 64;

  f32x4 acc[4][4];
#pragma unroll
  for (int i = 0; i < 4; ++i)
#pragma unroll
    for (int j = 0; j < 4; ++j) acc[i][j] = (f32x4){0.f, 0.f, 0.f, 0.f};

  for (int k0 = 0; k0 < K; k0 += 64) {
#pragma unroll
    for (int i = 0; i < 4; ++i) {
      int c = i * 256 + t;
      int row = c >> 3, col = (c & 7) * 8;
      gload16(Ab + (long)row * lda + k0 + col, &As[c * 8]);
      gload16(Bb + (long)row * ldb + k0 + col, &Bs[c * 8]);
    }
    if constexpr (FILL) {
      const f32x4 fv = {FILLV, FILLV, FILLV, FILLV};
      const int wg = blockIdx.y * gridDim.x + blockIdx.x;
      const long nB = (long)gridDim.x * gridDim.y;
      long s0 = fillBase + (((long)(k0 >> 6) * nB + wg) * 2) * 256 + t;
      __builtin_nontemporal_store(fv, (f32x4*)attn + s0);
      __builtin_nontemporal_store(fv, (f32x4*)attn + s0 + 256);
    }
    __syncthreads();
#pragma unroll
    for (int kk = 0; kk < 2; ++kk) {
      bf16x8 af[4], bfr[4];
#pragma unroll
      for (int mi = 0; mi < 4; ++mi)
        af[mi] = *(const bf16x8*)&As[(wm + mi * 16 + (lane & 15)) * 64
                                     + kk * 32 + (lane >> 4) * 8];
#pragma unroll
      for (int ni = 0; ni < 4; ++ni)
        bfr[ni] = *(const bf16x8*)&Bs[(wn + ni * 16 + (lane & 15)) * 64
                                      + kk * 32 + (lane >> 4) * 8];
#pragma unroll
      for (int mi = 0; mi < 4; ++mi)
#pragma unroll
        for (int ni = 0; ni < 4; ++ni)
          acc[mi][ni] = __builtin_amdgcn_mfma_f32_16x16x32_bf16(
              af[mi], bfr[ni], acc[mi][ni], 0, 0, 0);
    }
    __syncthreads();
  }

  const long cb = (long)zb * cBatchB + (long)zh * cBatchH;
  const int row0 = blockIdx.y * 128 + wm;
  const int col0 = blockIdx.x * 128 + wn;
#pragma unroll
  for (int mi = 0; mi < 4; ++mi) {
#pragma unroll
    for (int ni = 0; ni < 4; ++ni) {
      const int col = col0 + ni * 16 + (lane & 15);
      const float bv = BIAS ? bias[col] : 0.f;
#pragma unroll
      for (int j = 0; j < 4; ++j) {
        const int row = row0 + mi * 16 + (lane >> 4) * 4 + j;
        float v = acc[mi][ni][j] + bv;
        if (RELU) v = fmaxf(v, 0.f);
        if (OUTF32) ((float*)C)[cb + (long)row * ldc + col] = v;
        else        ((bf16_t*)C)[cb + (long)row * ldc + col] = (bf16_t)v;
      }
    }
  }
}

// ---------------------------------------------------------------------------
// Fused Q/K/V projection: A,Wt,bias,C all stacked; which = blockIdx.y>>5.
// Grid (16, 96). Also writes its share of the attn fill.
// ---------------------------------------------------------------------------
__global__ __launch_bounds__(256) void proj_gemm(
    const bf16_t* __restrict__ A,    // [12288][2048] stacked q,k,v (bf16)
    const bf16_t* __restrict__ Wt,   // [3][2048][2048] stacked Wq_t,Wk_t,Wv_t
    const float* __restrict__ bq, const float* __restrict__ bk,
    const float* __restrict__ bv,
    bf16_t* __restrict__ C,          // [12288][2048] stacked Qp,Kp,Vp
    float* __restrict__ attn)
{
  __shared__ bf16_t As[128 * 64];
  __shared__ bf16_t Bs[128 * 64];

  const int t = threadIdx.x;
  const int lane = t & 63, w = t >> 6;
  const int wm = (w >> 1) * 64, wn = (w & 1) * 64;
  const int which = blockIdx.y >> 5;
  const bf16_t* Ab = A + (long)blockIdx.y * 128 * 2048;
  const bf16_t* Bb = Wt + (long)which * 4194304
                        + (long)blockIdx.x * 128 * 2048;
  const float* bias = which == 0 ? bq : (which == 1 ? bk : bv);
  const int wg = blockIdx.y * 16 + blockIdx.x;   // 0..1535
  const f32x4 fv = {FILLV, FILLV, FILLV, FILLV};

  f32x4 acc[4][4];
#pragma unroll
  for (int i = 0; i < 4; ++i)
#pragma unroll
    for (int j = 0; j < 4; ++j) acc[i][j] = (f32x4){0.f, 0.f, 0.f, 0.f};

  for (int k0 = 0; k0 < 2048; k0 += 64) {
#pragma unroll
    for (int i = 0; i < 4; ++i) {
      int c = i * 256 + t;
      int row = c >> 3, col = (c & 7) * 8;
      gload16(Ab + (long)row * 2048 + k0 + col, &As[c * 8]);
      gload16(Bb + (long)row * 2048 + k0 + col, &Bs[c * 8]);
    }
    {
      long s0 = (((long)(k0 >> 6) * 1536 + wg) * 2) * 256 + t;
      __builtin_nontemporal_store(fv, (f32x4*)attn + s0);
      __builtin_nontemporal_store(fv, (f32x4*)attn + s0 + 256);
    }
    __syncthreads();
#pragma unroll
    for (int kk = 0; kk < 2; ++kk) {
      bf16x8 af[4], bfr[4];
#pragma unroll
      for (int mi = 0; mi < 4; ++mi)
        af[mi] = *(const bf16x8*)&As[(wm + mi * 16 + (lane & 15)) * 64
                                     + kk * 32 + (lane >> 4) * 8];
#pragma unroll
      for (int ni = 0; ni < 4; ++ni)
        bfr[ni] = *(const bf16x8*)&Bs[(wn + ni * 16 + (lane & 15)) * 64
                                      + kk * 32 + (lane >> 4) * 8];
#pragma unroll
      for (int mi = 0; mi < 4; ++mi)
#pragma unroll
        for (int ni = 0; ni < 4; ++ni)
          acc[mi][ni] = __builtin_amdgcn_mfma_f32_16x16x32_bf16(
              af[mi], bfr[ni], acc[mi][ni], 0, 0, 0);
    }
    __syncthreads();
  }

  const int row0 = blockIdx.y * 128 + wm;
  const int col0 = blockIdx.x * 128 + wn;
#pragma unroll
  for (int mi = 0; mi < 4; ++mi) {
#pragma unroll
    for (int ni = 0; ni < 4; ++ni) {
      const int col = col0 + ni * 16 + (lane & 15);
      const float bvv = bias[col];
#pragma unroll
      for (int j = 0; j < 4; ++j) {
        const int row = row0 + mi * 16 + (lane >> 4) * 4 + j;
        C[(long)row * 2048 + col] = (bf16_t)(acc[mi][ni][j] + bvv);
      }
    }
  }
}

// ---------------------------------------------------------------------------
// Fused per-head feature map: Out = relu(A @ Wf1 + b1) @ Wf2 + b2.
// A/Out are [131072][128]; block = 64 rows; H [64][256] in swizzled LDS;
// weights (128KB total) read from global (L2-hot).
// ---------------------------------------------------------------------------
__global__ __launch_bounds__(256) void fm_fused(
    const bf16_t* __restrict__ A, const bf16_t* __restrict__ W1t,
    const bf16_t* __restrict__ W2t, const float* __restrict__ b1,
    const float* __restrict__ b2, bf16_t* __restrict__ Out)
{
  __shared__ char Hs[64 * 256 * 2];   // 32 KB
  const int t = threadIdx.x, lane = t & 63, w = t >> 6;
  const long r0 = (long)blockIdx.x * 64;
  const int lr = lane & 15, lk = lane >> 4;

  // phase A: H[64][256] = relu(A[64][128] @ W1t^T + b1)
  f32x4 acc[4][4];
#pragma unroll
  for (int i = 0; i < 4; ++i)
#pragma unroll
    for (int j = 0; j < 4; ++j) acc[i][j] = (f32x4){0.f, 0.f, 0.f, 0.f};
  const int wn = w * 64;
#pragma unroll
  for (int kk = 0; kk < 4; ++kk) {
    bf16x8 af[4], bfr[4];
#pragma unroll
    for (int mi = 0; mi < 4; ++mi)
      af[mi] = *(const bf16x8*)&A[(r0 + mi * 16 + lr) * 128 + kk * 32 + lk * 8];
#pragma unroll
    for (int ni = 0; ni < 4; ++ni)
      bfr[ni] = *(const bf16x8*)&W1t[(long)(wn + ni * 16 + lr) * 128
                                     + kk * 32 + lk * 8];
#pragma unroll
    for (int mi = 0; mi < 4; ++mi)
#pragma unroll
      for (int ni = 0; ni < 4; ++ni)
        acc[mi][ni] = __builtin_amdgcn_mfma_f32_16x16x32_bf16(
            af[mi], bfr[ni], acc[mi][ni], 0, 0, 0);
  }
#pragma unroll
  for (int ni = 0; ni < 4; ++ni) {
    const int col = wn + ni * 16 + lr;
    const float bvv = b1[col];
#pragma unroll
    for (int mi = 0; mi < 4; ++mi)
#pragma unroll
      for (int j = 0; j < 4; ++j) {
        const int row = mi * 16 + lk * 4 + j;
        float h = fmaxf(acc[mi][ni][j] + bvv, 0.f);
        int byte = (row << 9) + (col << 1);
        byte ^= (row & 7) << 4;                 // bank-conflict swizzle (G4)
        *(bf16_t*)(Hs + byte) = (bf16_t)h;
      }
  }
  __syncthreads();

  // phase B: C[64][128] = H @ W2t^T + b2
  f32x4 acc2[4][2];
#pragma unroll
  for (int i = 0; i < 4; ++i)
#pragma unroll
    for (int j = 0; j < 2; ++j) acc2[i][j] = (f32x4){0.f, 0.f, 0.f, 0.f};
  const int wn2 = w * 32;
#pragma unroll
  for (int kk = 0; kk < 8; ++kk) {
    bf16x8 af[4], bfr[2];
#pragma unroll
    for (int mi = 0; mi < 4; ++mi) {
      const int m = mi * 16 + lr;
      int byte = (m << 9) + kk * 64 + lk * 16;
      byte ^= (m & 7) << 4;
      af[mi] = *(const bf16x8*)(Hs + byte);
    }
#pragma unroll
    for (int ni = 0; ni < 2; ++ni)
      bfr[ni] = *(const bf16x8*)&W2t[(long)(wn2 + ni * 16 + lr) * 256
                                     + kk * 32 + lk * 8];
#pragma unroll
    for (int mi = 0; mi < 4; ++mi)
#pragma unroll
      for (int ni = 0; ni < 2; ++ni)
        acc2[mi][ni] = __builtin_amdgcn_mfma_f32_16x16x32_bf16(
            af[mi], bfr[ni], acc2[mi][ni], 0, 0, 0);
  }
#pragma unroll
  for (int ni = 0; ni < 2; ++ni) {
    const int col = wn2 + ni * 16 + lr;
    const float bvv = b2[col];
#pragma unroll
    for (int mi = 0; mi < 4; ++mi)
#pragma unroll
      for (int j = 0; j < 4; ++j) {
        const int row = mi * 16 + lk * 4 + j;
        Out[(r0 + row) * 128 + col] = (bf16_t)(acc2[mi][ni][j] + bvv);
      }
  }
}

// ---------------------------------------------------------------------------
__global__ void cvt3(const float* __restrict__ q, const float* __restrict__ k,
                     const float* __restrict__ v, bf16_t* __restrict__ out) {
  const float* in = blockIdx.y == 0 ? q : (blockIdx.y == 1 ? k : v);
  bf16_t* o = out + (long)blockIdx.y * 8388608L;
  long i = ((long)blockIdx.x * 256 + threadIdx.x) * 4;
  float4 x = *(const float4*)&in[i];
  bf16x4 r = {(bf16_t)x.x, (bf16_t)x.y, (bf16_t)x.z, (bf16_t)x.w};
  *(bf16x4*)&o[i] = r;
}

// four 2048x2048 W[K][N] fp32 -> Wt[N][K] bf16, stacked output
__global__ void transpose_cvt4(const float* __restrict__ W0,
                               const float* __restrict__ W1,
                               const float* __restrict__ W2,
                               const float* __restrict__ W3,
                               bf16_t* __restrict__ Wt) {
  const float* W = blockIdx.z == 0 ? W0 : blockIdx.z == 1 ? W1
                 : blockIdx.z == 2 ? W2 : W3;
  bf16_t* out = Wt + (long)blockIdx.z * 4194304L;
  __shared__ float tile[32][33];
  const int n0 = blockIdx.x * 32, k0 = blockIdx.y * 32;
  const int x = threadIdx.x, y = threadIdx.y;
#pragma unroll
  for (int j = 0; j < 32; j += 8)
    tile[y + j][x] = W[(long)(k0 + y + j) * 2048 + n0 + x];
  __syncthreads();
#pragma unroll
  for (int j = 0; j < 32; j += 8)
    out[(long)(n0 + y + j) * 2048 + k0 + x] = (bf16_t)tile[x][y + j];
}

// small W[Kd][Nd] fp32 -> Wt[Nd][Kd] bf16
__global__ void transpose_cvt(const float* __restrict__ W,
                              bf16_t* __restrict__ Wt, int Kd, int Nd) {
  __shared__ float tile[32][33];
  const int n0 = blockIdx.x * 32, k0 = blockIdx.y * 32;
  const int x = threadIdx.x, y = threadIdx.y;
#pragma unroll
  for (int j = 0; j < 32; j += 8)
    tile[y + j][x] = W[(long)(k0 + y + j) * Nd + n0 + x];
  __syncthreads();
#pragma unroll
  for (int j = 0; j < 32; j += 8)
    Wt[(long)(n0 + y + j) * Kd + k0 + x] = (bf16_t)tile[x][y + j];
}

// denom[z=b*16+h] = sum over (s,d) of Kf + 1e-8
__global__ void denom_kernel(const bf16_t* __restrict__ Kf,
                             float* __restrict__ denom) {
  const int z = blockIdx.x, b = z >> 4, h = z & 15;
  const bf16_t* base = Kf + (long)b * 2048 * 2048 + h * 128;
  const int t = threadIdx.x;
  float s = 0.f;
  for (int i = t; i < 2048 * 16; i += 256) {
    int r = i >> 4, seg = i & 15;
    bf16x8 v = *(const bf16x8*)&base[(long)r * 2048 + seg * 8];
#pragma unroll
    for (int j = 0; j < 8; ++j) s += (float)v[j];
  }
#pragma unroll
  for (int off = 32; off; off >>= 1) s += __shfl_down(s, off, 64);
  __shared__ float red[4];
  if ((t & 63) == 0) red[t >> 6] = s;
  __syncthreads();
  if (t == 0) denom[z] = red[0] + red[1] + red[2] + red[3] + 1e-8f;
}

// Partial KV^T: part[sch][z][e][d] = sum_{s in chunk} V[s,e] * K[s,d]
__global__ __launch_bounds__(256) void kv_partial(
    const bf16_t* __restrict__ Kf, const bf16_t* __restrict__ Vp,
    float* __restrict__ part) {
  const int z = blockIdx.y, b = z >> 4, h = z & 15;
  const int s0 = blockIdx.x * 128;
  const int t = threadIdx.x;
  __shared__ bf16_t Ks[32 * 128];
  __shared__ bf16_t Vs[32 * 128];
  const bf16_t* Kb = Kf + (long)b * 4194304 + h * 128;
  const bf16_t* Vb = Vp + (long)b * 4194304 + h * 128;
  float acc[8][8];
#pragma unroll
  for (int i = 0; i < 8; ++i)
#pragma unroll
    for (int j = 0; j < 8; ++j) acc[i][j] = 0.f;
  const int d0 = (t & 15) * 8, e0 = (t >> 4) * 8;
  for (int sc = 0; sc < 128; sc += 32) {
#pragma unroll
    for (int i = 0; i < 2; ++i) {
      int idx = (i * 256 + t) * 8;
      int r = idx >> 7, c = idx & 127;
      long g = (long)(s0 + sc + r) * 2048 + c;
      *(bf16x8*)&Ks[r * 128 + c] = *(const bf16x8*)&Kb[g];
      *(bf16x8*)&Vs[r * 128 + c] = *(const bf16x8*)&Vb[g];
    }
    __syncthreads();
    for (int s = 0; s < 32; ++s) {
      bf16x8 kv = *(const bf16x8*)&Ks[s * 128 + d0];
      bf16x8 vv = *(const bf16x8*)&Vs[s * 128 + e0];
      float kf[8], vf[8];
#pragma unroll
      for (int i = 0; i < 8; ++i) { kf[i] = (float)kv[i]; vf[i] = (float)vv[i]; }
#pragma unroll
      for (int i = 0; i < 8; ++i)
#pragma unroll
        for (int j = 0; j < 8; ++j) acc[i][j] += vf[i] * kf[j];
    }
    __syncthreads();
  }
  float* pb = part + ((long)blockIdx.x * 32 + z) * 16384;
#pragma unroll
  for (int i = 0; i < 8; ++i)
#pragma unroll
    for (int j = 0; j < 8; ++j)
      pb[(e0 + i) * 128 + (d0 + j)] = acc[i][j];
}

// KVT[z][e][d] = (sum_sch part) / denom[z], as bf16
__global__ void kv_reduce(const float* __restrict__ part,
                          const float* __restrict__ denom,
                          bf16_t* __restrict__ KVT) {
  const int z = blockIdx.x;
  const float inv = 1.0f / denom[z];
  for (int i = threadIdx.x; i < 16384; i += 256) {
    float s = 0.f;
#pragma unroll
    for (int c = 0; c < 16; ++c) s += part[((long)c * 32 + z) * 16384 + i];
    KVT[(long)z * 16384 + i] = (bf16_t)(s * inv);
  }
}

// ---------------------------------------------------------------------------
extern "C" void kernel_launch(void* const* d_in, const int* in_sizes, int n_in,
                              void* d_out, int out_size, void* d_ws, size_t ws_size,
                              hipStream_t stream) {
  (void)in_sizes; (void)n_in; (void)out_size; (void)ws_size;
  const float* q   = (const float*)d_in[0];
  const float* k   = (const float*)d_in[1];
  const float* v   = (const float*)d_in[2];
  const float* Wq  = (const float*)d_in[3];
  const float* bq  = (const float*)d_in[4];
  const float* Wk  = (const float*)d_in[5];
  const float* bk  = (const float*)d_in[6];
  const float* Wv  = (const float*)d_in[7];
  const float* bv  = (const float*)d_in[8];
  const float* Wo  = (const float*)d_in[9];
  const float* bo  = (const float*)d_in[10];
  const float* Wf1 = (const float*)d_in[11];
  const float* bf1 = (const float*)d_in[12];
  const float* Wf2 = (const float*)d_in[13];
  const float* bf2 = (const float*)d_in[14];

  // ws layout (bf16 element offsets)
  bf16_t* P     = (bf16_t*)d_ws;
  bf16_t* qkv_bf = P;                  // [3][4096][2048] stacked q,k,v bf16
  bf16_t* Wqkv_t = P + 25165824L;      // [4][2048][2048] Wq_t,Wk_t,Wv_t,Wo_t
  bf16_t* Wo_t   = P + 37748736L;
  bf16_t* Wf1_t  = P + 41943040L;      // [256][128]
  bf16_t* Wf2_t  = P + 41975808L;      // [128][256]
  bf16_t* Qp     = P + 42008576L;      // [12288][2048] stacked Qp,Kp,Vp
  bf16_t* Kp     = P + 50397184L;
  bf16_t* Vp     = P + 58785792L;      // later reused as context
  bf16_t* Qf     = P + 83951616L;      // [131072][128] stacked Qf,Kf
  bf16_t* Kf     = P + 92340224L;
  bf16_t* KVT    = P + 100728832L;     // [32][128][128]
  float*  denom  = (float*)(P + 101253120L);
  float*  part   = (float*)d_ws;       // [16][32][128][128] f32 over dead qkv_bf

  float* out0 = (float*)d_out;                 // [2,2048,2048]
  float* attn = (float*)d_out + 8388608L;      // [2,16,2048,2048]

  dim3 blk(256);

  // fp32 -> bf16 (q,k,v stacked)
  cvt3<<<dim3(8192, 3), blk, 0, stream>>>(q, k, v, qkv_bf);

  // weight transposes
  transpose_cvt4<<<dim3(64, 64, 4), dim3(32, 8), 0, stream>>>(
      Wq, Wk, Wv, Wo, Wqkv_t);
  transpose_cvt<<<dim3(8, 4), dim3(32, 8), 0, stream>>>(Wf1, Wf1_t, 128, 256);
  transpose_cvt<<<dim3(4, 8), dim3(32, 8), 0, stream>>>(Wf2, Wf2_t, 256, 128);

  // fused Q/K/V projection (+ attn fill part 1: slots [0, 25165824))
  proj_gemm<<<dim3(16, 96), blk, 0, stream>>>(
      qkv_bf, Wqkv_t, bq, bk, bv, Qp, attn);

  // fused feature map over Qp||Kp -> Qf||Kf
  fm_fused<<<2048, blk, 0, stream>>>(Qp, Wf1_t, Wf2_t, bf1, bf2, Qf);

  // denominator per (b,h)
  denom_kernel<<<32, blk, 0, stream>>>(Kf, denom);

  // KV^T = V^T K per head (split-S partials, then reduce + 1/denom scale)
  kv_partial<<<dim3(16, 32), blk, 0, stream>>>(Kf, Vp, part);
  kv_reduce<<<32, blk, 0, stream>>>(part, denom, KVT);

  // context = Qf @ KVT^T (batched over 32 (b,h)); overwrite Vp region
  gemm_bt<false, false, false, false><<<dim3(1, 16, 32), blk, 0, stream>>>(
      Qf, KVT, nullptr, Vp, 128, 2048, 128, 2048,
      4194304L, 128L, 262144L, 16384L, 4194304L, 128L, 16,
      nullptr, 0);

  // output = context @ Wo + bo (+ attn fill part 2: slots [25165824, 33554432))
  gemm_bt<false, true, true, true><<<dim3(16, 32, 1), blk, 0, stream>>>(
      Vp, Wo_t, bo, out0, 2048, 2048, 2048, 2048, 0, 0, 0, 0, 0, 0, 1,
      attn, 25165824L);
}